// Round 2
// baseline (6057.325 us; speedup 1.0000x reference)
//
#include <hip/hip_runtime.h>
#include <cstdint>

#define NN 2000     // nodes
#define NP 2048     // padded nodes
#define TT 12
#define BBATCH 32
#define HH 64
#define EE 10

typedef _Float16 f16;
typedef _Float16 f16x8 __attribute__((ext_vector_type(8)));
typedef float f32x4 __attribute__((ext_vector_type(4)));
typedef unsigned int u32;

// async global->LDS, 16B per lane; lds must be wave-uniform base (HW adds lane*16)
__device__ __forceinline__ void gld_lds16(const void* g, void* lds) {
    __builtin_amdgcn_global_load_lds(
        (const __attribute__((address_space(1))) u32*)(const void*)g,
        (__attribute__((address_space(3))) u32*)(void*)lds, 16, 0, 0);
}

// ---------------- supports: A = softmax(relu(emb @ emb^T)), fp16, padded [NP][NP] ----------------
__global__ __launch_bounds__(256) void k_supports(const float* __restrict__ emb, f16* __restrict__ A2) {
    int n = blockIdx.x;
    int tid = threadIdx.x;
    if (n >= NN) {
        for (int m = tid; m < NP; m += 256) A2[(size_t)n * NP + m] = (f16)0.f;
        return;
    }
    __shared__ float red[4];
    float en[EE];
#pragma unroll
    for (int e = 0; e < EE; e++) en[e] = emb[n * EE + e];
    float g[8];
    float mx = 0.f;
#pragma unroll
    for (int i = 0; i < 8; i++) {
        int m = tid + 256 * i;
        float v = 0.f;
        if (m < NN) {
            float a = 0.f;
#pragma unroll
            for (int e = 0; e < EE; e++) a += en[e] * emb[m * EE + e];
            v = fmaxf(a, 0.f);
            mx = fmaxf(mx, v);
        }
        g[i] = v;
    }
#pragma unroll
    for (int d = 32; d; d >>= 1) mx = fmaxf(mx, __shfl_xor(mx, d));
    if ((tid & 63) == 0) red[tid >> 6] = mx;
    __syncthreads();
    mx = fmaxf(fmaxf(red[0], red[1]), fmaxf(red[2], red[3]));
    float s = 0.f;
#pragma unroll
    for (int i = 0; i < 8; i++) {
        int m = tid + 256 * i;
        if (m < NN) { g[i] = __expf(g[i] - mx); s += g[i]; }
    }
#pragma unroll
    for (int d = 32; d; d >>= 1) s += __shfl_xor(s, d);
    __syncthreads();
    if ((tid & 63) == 0) red[tid >> 6] = s;
    __syncthreads();
    s = red[0] + red[1] + red[2] + red[3];
    float inv = 1.f / s;
#pragma unroll
    for (int i = 0; i < 8; i++) {
        int m = tid + 256 * i;
        A2[(size_t)n * NP + m] = (m < NN) ? (f16)(g[i] * inv) : (f16)0.f;
    }
}

// ---------------- wgen: W^T[n][o][r] = sum_e emb[n,e] * wpool[e,k(r),c(r),o]  (fp16) ----------------
// r in [0,R): k = r>=DPAD, c = r - k*DPAD, zero if c>=DIN. 4 nodes per block to reuse pool loads.
template <int DIN, int O>
__global__ __launch_bounds__(256) void k_wgen(const float* __restrict__ emb,
                                              const float* __restrict__ wpool,
                                              f16* __restrict__ WT) {
    constexpr int DPAD = (DIN == 66) ? 80 : 128;
    constexpr int R = 2 * DPAD;
    int n0 = blockIdx.x * 4;
    int r = threadIdx.x;
    if (r >= R) return;
    int k = (r >= DPAD) ? 1 : 0;
    int c = r - k * DPAD;
    bool valid = (c < DIN);
    float en[4][EE];
#pragma unroll
    for (int j = 0; j < 4; j++)
#pragma unroll
        for (int e = 0; e < EE; e++) en[j][e] = emb[(n0 + j) * EE + e];
    const float* wp = wpool + ((size_t)(k * DIN + (valid ? c : 0))) * O;
    for (int o = 0; o < O; o += 4) {
        float4 a[4] = {};
        if (valid) {
#pragma unroll
            for (int e = 0; e < EE; e++) {
                float4 w4 = *(const float4*)(wp + (size_t)e * 2 * DIN * O + o);
#pragma unroll
                for (int j = 0; j < 4; j++) {
                    a[j].x += en[j][e] * w4.x; a[j].y += en[j][e] * w4.y;
                    a[j].z += en[j][e] * w4.z; a[j].w += en[j][e] * w4.w;
                }
            }
        }
#pragma unroll
        for (int j = 0; j < 4; j++) {
            f16* outp = WT + ((size_t)(n0 + j) * O + o) * R + r;
            outp[0] = (f16)a[j].x; outp[(size_t)R] = (f16)a[j].y;
            outp[(size_t)2 * R] = (f16)a[j].z; outp[(size_t)3 * R] = (f16)a[j].w;
        }
    }
}

// ---------------- pack layer0 x_t into xs0/us0 (row-major) and xsT0 (channel-major) ----------------
__global__ __launch_bounds__(256) void k_pack(const float* __restrict__ x, int t,
                                              f16* __restrict__ xs, f16* __restrict__ us,
                                              f16* __restrict__ xsT) {
    int idx = blockIdx.x * 256 + threadIdx.x;  // over b*2*NN, n fastest
    if (idx >= BBATCH * 2 * NN) return;
    int n = idx % NN;
    int bd = idx / NN;
    int d = bd & 1, b = bd >> 1;
    float v = x[(((size_t)b * TT + t) * NN + n) * 2 + d];
    f16 h = (f16)v;
    xs[(size_t)n * (BBATCH * 66) + b * 66 + d] = h;
    us[(size_t)n * (BBATCH * 66) + b * 66 + d] = h;
    xsT[(size_t)(b * 66 + d) * NP + n] = h;
}

// ---------------- aggregation GEMM: C[2048][J] = A2[2048][2048] @ XT[J][2048]^T (fp16 in/out) ------
// 128x64 tile, BK=64, 4 waves, global_load_lds staging, st_16x32 XOR swizzle both sides.
__global__ __launch_bounds__(256) void k_gemm(const f16* __restrict__ A2, const f16* __restrict__ XT,
                                              f16* __restrict__ C, int J) {
    __shared__ __align__(16) f16 at[128 * 64];
    __shared__ __align__(16) f16 xt[64 * 64];
    int tj = blockIdx.x * 64;
    int tm = blockIdx.y * 128;
    int tid = threadIdx.x;
    int w = tid >> 6, l = tid & 63;
    int lr = l & 15, lg = l >> 4;
    f32x4 acc[2][4];
#pragma unroll
    for (int mt = 0; mt < 2; mt++)
#pragma unroll
        for (int nt = 0; nt < 4; nt++) acc[mt][nt] = (f32x4){0.f, 0.f, 0.f, 0.f};

    for (int k0 = 0; k0 < 2048; k0 += 64) {
        // stage A tile: 16KB, wave w covers elems [w*2048, w*2048+2048)
#pragma unroll
        for (int i = 0; i < 4; i++) {
            int e = w * 2048 + i * 512 + l * 8;
            int row = e >> 6, s = (e >> 3) & 7;
            const f16* src = A2 + (size_t)(tm + row) * 2048 + k0 + ((s ^ (row & 7)) << 3);
            gld_lds16(src, &at[w * 2048 + i * 512]);
        }
        // stage X tile: 8KB
#pragma unroll
        for (int i = 0; i < 2; i++) {
            int e = w * 1024 + i * 512 + l * 8;
            int row = e >> 6, s = (e >> 3) & 7;
            const f16* src = XT + (size_t)(tj + row) * 2048 + k0 + ((s ^ (row & 7)) << 3);
            gld_lds16(src, &xt[w * 1024 + i * 512]);
        }
        __syncthreads();
#pragma unroll
        for (int kk = 0; kk < 2; kk++) {
            int s = kk * 4 + lg;
            f16x8 av[2], bv[4];
#pragma unroll
            for (int mt = 0; mt < 2; mt++) {
                int row = w * 32 + mt * 16 + lr;
                av[mt] = *(const f16x8*)&at[row * 64 + ((s ^ (row & 7)) << 3)];
            }
#pragma unroll
            for (int nt = 0; nt < 4; nt++) {
                int row = nt * 16 + lr;
                bv[nt] = *(const f16x8*)&xt[row * 64 + ((s ^ (row & 7)) << 3)];
            }
#pragma unroll
            for (int mt = 0; mt < 2; mt++)
#pragma unroll
                for (int nt = 0; nt < 4; nt++)
                    acc[mt][nt] = __builtin_amdgcn_mfma_f32_16x16x32_f16(av[mt], bv[nt], acc[mt][nt], 0, 0, 0);
        }
        __syncthreads();
    }
#pragma unroll
    for (int mt = 0; mt < 2; mt++)
#pragma unroll
        for (int nt = 0; nt < 4; nt++)
#pragma unroll
            for (int q = 0; q < 4; q++) {
                int row = tm + w * 32 + mt * 16 + lg * 4 + q;
                int col = tj + nt * 16 + lr;
                C[(size_t)row * J + col] = (f16)acc[mt][nt][q];
            }
}

// ---------------- fused per-node gate: zr = sigmoid(xg @ W + b); u = z*h; store u, r ---------------
template <int L>
__global__ __launch_bounds__(256) void k_gate(const f16* __restrict__ xs_rm, const f16* __restrict__ agg,
                                              const f16* __restrict__ WT, const float* __restrict__ bpool,
                                              const float* __restrict__ emb, const float* __restrict__ hbuf,
                                              f16* __restrict__ us_rm, f16* __restrict__ usT,
                                              float* __restrict__ rbuf) {
    constexpr int DIN = L ? 128 : 66, CIN = L ? 64 : 2, DPAD = L ? 128 : 80;
    constexpr int R = 2 * DPAD, RPAD = R + 8, KCH = R / 32;
    constexpr int O = 128;
    int n = blockIdx.x;
    int tid = threadIdx.x, w = tid >> 6, l = tid & 63;
    int lr = l & 15, lg = l >> 4;
    __shared__ __align__(16) f16 xg[32 * RPAD];

    // prefetch W fragments (B operand): WT[n][o][r], contiguous along r
    f16x8 wf[KCH][2];
    const f16* wbase = WT + (size_t)n * O * R;
#pragma unroll
    for (int kk = 0; kk < KCH; kk++)
#pragma unroll
        for (int nt = 0; nt < 2; nt++) {
            int o = w * 32 + nt * 16 + lr;
            wf[kk][nt] = *(const f16x8*)(wbase + (size_t)o * R + kk * 32 + lg * 8);
        }
    // zero LDS then stage
    for (int i = tid; i < 32 * RPAD / 8; i += 256) *(float4*)&xg[i * 8] = (float4){0.f, 0.f, 0.f, 0.f};
    __syncthreads();
    if (L == 0) {
        for (int e = tid; e < 32 * DIN; e += 256) {
            int b = e / DIN, c = e % DIN;
            xg[b * RPAD + c] = xs_rm[(size_t)n * 32 * DIN + e];
            xg[b * RPAD + DPAD + c] = agg[(size_t)n * 32 * DIN + e];
        }
    } else {
        for (int e8 = tid; e8 < 32 * DIN / 8; e8 += 256) {
            int b = e8 >> 4, c8 = e8 & 15;
            *(f16x8*)&xg[b * RPAD + c8 * 8] = *(const f16x8*)&xs_rm[(size_t)n * 32 * DIN + e8 * 8];
            *(f16x8*)&xg[b * RPAD + DPAD + c8 * 8] = *(const f16x8*)&agg[(size_t)n * 32 * DIN + e8 * 8];
        }
    }
    __syncthreads();

    f32x4 acc[2][2];
#pragma unroll
    for (int mt = 0; mt < 2; mt++)
#pragma unroll
        for (int nt = 0; nt < 2; nt++) acc[mt][nt] = (f32x4){0.f, 0.f, 0.f, 0.f};
#pragma unroll
    for (int kk = 0; kk < KCH; kk++) {
        f16x8 av[2];
#pragma unroll
        for (int mt = 0; mt < 2; mt++)
            av[mt] = *(const f16x8*)&xg[(mt * 16 + lr) * RPAD + kk * 32 + lg * 8];
#pragma unroll
        for (int mt = 0; mt < 2; mt++)
#pragma unroll
            for (int nt = 0; nt < 2; nt++)
                acc[mt][nt] = __builtin_amdgcn_mfma_f32_16x16x32_f16(av[mt], wf[kk][nt], acc[mt][nt], 0, 0, 0);
    }
    float bias[2];
#pragma unroll
    for (int nt = 0; nt < 2; nt++) {
        int o = w * 32 + nt * 16 + lr;
        float bs = 0.f;
#pragma unroll
        for (int e = 0; e < EE; e++) bs += emb[n * EE + e] * bpool[e * 2 * HH + o];
        bias[nt] = bs;
    }
#pragma unroll
    for (int mt = 0; mt < 2; mt++)
#pragma unroll
        for (int nt = 0; nt < 2; nt++)
#pragma unroll
            for (int q = 0; q < 4; q++) {
                int o = w * 32 + nt * 16 + lr;
                int b = mt * 16 + lg * 4 + q;
                float v = acc[mt][nt][q] + bias[nt];
                float sg = 1.f / (1.f + __expf(-v));
                if (o < HH) {  // z half
                    float u = sg * hbuf[((size_t)n * 32 + b) * HH + o];
                    f16 uh = (f16)u;
                    us_rm[(size_t)n * 32 * DIN + b * DIN + CIN + o] = uh;
                    usT[(size_t)(b * HH + o) * NP + n] = uh;
                } else {       // r half
                    rbuf[((size_t)n * 32 + b) * HH + (o - HH)] = sg;
                }
            }
}

// ---------------- fused per-node update: hc = tanh(xg @ W + b); h' = r*h + (1-r)*hc ---------------
template <int L>
__global__ __launch_bounds__(256) void k_upd(const f16* __restrict__ us_rm, const f16* __restrict__ agg,
                                             const f16* __restrict__ uagg, const f16* __restrict__ WT,
                                             const float* __restrict__ bpool, const float* __restrict__ emb,
                                             float* hbuf, const float* __restrict__ rbuf,
                                             f16* xs_self, f16* xsT_self,
                                             f16* xsn, f16* xsTn, f16* usn,
                                             float* dout, int t) {
    constexpr int DIN = L ? 128 : 66, CIN = L ? 64 : 2, DPAD = L ? 128 : 80;
    constexpr int R = 2 * DPAD, RPAD = R + 8, KCH = R / 32;
    constexpr int O = 64;
    int n = blockIdx.x;
    int tid = threadIdx.x, w = tid >> 6, l = tid & 63;
    int lr = l & 15, lg = l >> 4;
    __shared__ __align__(16) f16 xg[32 * RPAD];

    f16x8 wf[KCH];
    const f16* wbase = WT + (size_t)n * O * R;
    int o = w * 16 + lr;
#pragma unroll
    for (int kk = 0; kk < KCH; kk++)
        wf[kk] = *(const f16x8*)(wbase + (size_t)o * R + kk * 32 + lg * 8);

    for (int i = tid; i < 32 * RPAD / 8; i += 256) *(float4*)&xg[i * 8] = (float4){0.f, 0.f, 0.f, 0.f};
    __syncthreads();
    if (L == 0) {
        for (int e = tid; e < 32 * DIN; e += 256) {
            int b = e / DIN, c = e % DIN;
            xg[b * RPAD + c] = us_rm[(size_t)n * 32 * DIN + e];
            f16 v = (c < CIN) ? agg[(size_t)n * 32 * DIN + b * DIN + c]
                              : uagg[(size_t)n * 32 * HH + b * HH + (c - CIN)];
            xg[b * RPAD + DPAD + c] = v;
        }
    } else {
        for (int e8 = tid; e8 < 32 * DIN / 8; e8 += 256) {
            int b = e8 >> 4, c8 = e8 & 15;
            *(f16x8*)&xg[b * RPAD + c8 * 8] = *(const f16x8*)&us_rm[(size_t)n * 32 * DIN + e8 * 8];
            f16x8 v = (c8 < 8) ? *(const f16x8*)&agg[(size_t)n * 32 * DIN + b * DIN + c8 * 8]
                               : *(const f16x8*)&uagg[(size_t)n * 32 * HH + b * HH + (c8 - 8) * 8];
            *(f16x8*)&xg[b * RPAD + DPAD + c8 * 8] = v;
        }
    }
    __syncthreads();

    f32x4 acc[2];
    acc[0] = (f32x4){0.f, 0.f, 0.f, 0.f};
    acc[1] = (f32x4){0.f, 0.f, 0.f, 0.f};
#pragma unroll
    for (int kk = 0; kk < KCH; kk++) {
        f16x8 av[2];
#pragma unroll
        for (int mt = 0; mt < 2; mt++)
            av[mt] = *(const f16x8*)&xg[(mt * 16 + lr) * RPAD + kk * 32 + lg * 8];
#pragma unroll
        for (int mt = 0; mt < 2; mt++)
            acc[mt] = __builtin_amdgcn_mfma_f32_16x16x32_f16(av[mt], wf[kk], acc[mt], 0, 0, 0);
    }
    float bias = 0.f;
#pragma unroll
    for (int e = 0; e < EE; e++) bias += emb[n * EE + e] * bpool[e * HH + o];
#pragma unroll
    for (int mt = 0; mt < 2; mt++)
#pragma unroll
        for (int q = 0; q < 4; q++) {
            int b = mt * 16 + lg * 4 + q;
            float v = acc[mt][q] + bias;
            float ex = __expf(2.f * v);
            float hc = 1.f - 2.f / (ex + 1.f);  // tanh
            size_t hidx = ((size_t)n * 32 + b) * HH + o;
            float r = rbuf[hidx], h = hbuf[hidx];
            float hn = r * h + (1.f - r) * hc;
            hbuf[hidx] = hn;
            f16 hh = (f16)hn;
            xs_self[(size_t)n * 32 * DIN + b * DIN + CIN + o] = hh;
            xsT_self[(size_t)(b * DIN + CIN + o) * NP + n] = hh;
            if (L == 0) {
                xsn[(size_t)n * 32 * 128 + b * 128 + o] = hh;
                xsTn[(size_t)(b * 128 + o) * NP + n] = hh;
                usn[(size_t)n * 32 * 128 + b * 128 + o] = hh;
            } else {
                dout[(((size_t)b * TT + t) * NN + n) * HH + o] = hn;
                if (t == TT - 1)
                    dout[(size_t)BBATCH * TT * NN * HH + ((size_t)b * NN + n) * HH + o] = hn;
            }
        }
}

extern "C" void kernel_launch(void* const* d_in, const int* in_sizes, int n_in,
                              void* d_out, int out_size, void* d_ws, size_t ws_size,
                              hipStream_t stream) {
    (void)in_sizes; (void)n_in; (void)out_size; (void)ws_size;
    const float* x   = (const float*)d_in[0];
    const float* emb = (const float*)d_in[1];
    const float* gw0 = (const float*)d_in[2];
    const float* gb0 = (const float*)d_in[3];
    const float* uw0 = (const float*)d_in[4];
    const float* ub0 = (const float*)d_in[5];
    const float* gw1 = (const float*)d_in[6];
    const float* gb1 = (const float*)d_in[7];
    const float* uw1 = (const float*)d_in[8];
    const float* ub1 = (const float*)d_in[9];
    float* out = (float*)d_out;

    char* p = (char*)d_ws;
    auto alloc = [&](size_t bytes) { char* r = p; p += (bytes + 255) & ~(size_t)255; return r; };
    f16* A2    = (f16*)alloc((size_t)NP * NP * 2);
    f16* Wg0   = (f16*)alloc((size_t)NN * 128 * 160 * 2);
    f16* Wu0   = (f16*)alloc((size_t)NN * 64 * 160 * 2);
    f16* Wg1   = (f16*)alloc((size_t)NN * 128 * 256 * 2);
    f16* Wu1   = (f16*)alloc((size_t)NN * 64 * 256 * 2);
    f16* xs0   = (f16*)alloc((size_t)NN * 32 * 66 * 2);
    f16* xsT0  = (f16*)alloc((size_t)2112 * NP * 2);
    f16* agg0  = (f16*)alloc((size_t)NP * 2112 * 2);
    f16* us0   = (f16*)alloc((size_t)NN * 32 * 66 * 2);
    f16* usT0  = (f16*)alloc((size_t)2048 * NP * 2);
    f16* uagg0 = (f16*)alloc((size_t)NP * 2048 * 2);
    f16* xs1   = (f16*)alloc((size_t)NN * 32 * 128 * 2);
    f16* xsT1  = (f16*)alloc((size_t)4096 * NP * 2);
    f16* agg1  = (f16*)alloc((size_t)NP * 4096 * 2);
    f16* us1   = (f16*)alloc((size_t)NN * 32 * 128 * 2);
    f16* usT1  = (f16*)alloc((size_t)2048 * NP * 2);
    f16* uagg1 = (f16*)alloc((size_t)NP * 2048 * 2);
    float* h0  = (float*)alloc((size_t)NN * 32 * 64 * 4);
    float* r0  = (float*)alloc((size_t)NN * 32 * 64 * 4);
    float* h1  = (float*)alloc((size_t)NN * 32 * 64 * 4);
    float* r1  = (float*)alloc((size_t)NN * 32 * 64 * 4);

    hipMemsetAsync(xs0, 0, (size_t)NN * 32 * 66 * 2, stream);
    hipMemsetAsync(xsT0, 0, (size_t)2112 * NP * 2, stream);
    hipMemsetAsync(xs1, 0, (size_t)NN * 32 * 128 * 2, stream);
    hipMemsetAsync(xsT1, 0, (size_t)4096 * NP * 2, stream);
    hipMemsetAsync(h0, 0, (size_t)NN * 32 * 64 * 4, stream);
    hipMemsetAsync(h1, 0, (size_t)NN * 32 * 64 * 4, stream);

    k_supports<<<NP, 256, 0, stream>>>(emb, A2);
    k_wgen<66, 128><<<NN / 4, 256, 0, stream>>>(emb, gw0, Wg0);
    k_wgen<66, 64><<<NN / 4, 256, 0, stream>>>(emb, uw0, Wu0);
    k_wgen<128, 128><<<NN / 4, 256, 0, stream>>>(emb, gw1, Wg1);
    k_wgen<128, 64><<<NN / 4, 256, 0, stream>>>(emb, uw1, Wu1);

    for (int t = 0; t < TT; t++) {
        // ---- layer 0 ----
        k_pack<<<500, 256, 0, stream>>>(x, t, xs0, us0, xsT0);
        k_gemm<<<dim3(2112 / 64, 16), 256, 0, stream>>>(A2, xsT0, agg0, 2112);
        k_gate<0><<<NN, 256, 0, stream>>>(xs0, agg0, Wg0, gb0, emb, h0, us0, usT0, r0);
        k_gemm<<<dim3(2048 / 64, 16), 256, 0, stream>>>(A2, usT0, uagg0, 2048);
        k_upd<0><<<NN, 256, 0, stream>>>(us0, agg0, uagg0, Wu0, ub0, emb, h0, r0,
                                         xs0, xsT0, xs1, xsT1, us1, nullptr, t);
        // ---- layer 1 ----
        k_gemm<<<dim3(4096 / 64, 16), 256, 0, stream>>>(A2, xsT1, agg1, 4096);
        k_gate<1><<<NN, 256, 0, stream>>>(xs1, agg1, Wg1, gb1, emb, h1, us1, usT1, r1);
        k_gemm<<<dim3(2048 / 64, 16), 256, 0, stream>>>(A2, usT1, uagg1, 2048);
        k_upd<1><<<NN, 256, 0, stream>>>(us1, agg1, uagg1, Wu1, ub1, emb, h1, r1,
                                         xs1, xsT1, nullptr, nullptr, nullptr, out, t);
    }
}

// Round 4
// 4321.597 us; speedup vs baseline: 1.4016x; 1.4016x over previous
//
#include <hip/hip_runtime.h>
#include <cstdint>

#define NN 2000     // nodes
#define NP 2048     // padded nodes
#define TT 12
#define BBATCH 32
#define HH 64
#define EE 10

typedef _Float16 f16;
typedef _Float16 f16x8 __attribute__((ext_vector_type(8)));
typedef float f32x4 __attribute__((ext_vector_type(4)));
typedef unsigned int u32;

// async global->LDS, 16B per lane; lds must be wave-uniform base (HW adds lane*16)
__device__ __forceinline__ void gld_lds16(const void* g, void* lds) {
    __builtin_amdgcn_global_load_lds(
        (const __attribute__((address_space(1))) u32*)(const void*)g,
        (__attribute__((address_space(3))) u32*)(void*)lds, 16, 0, 0);
}

// ---------------- supports: A = softmax(relu(emb @ emb^T)), fp16, padded [NP][NP] ----------------
__global__ __launch_bounds__(256) void k_supports(const float* __restrict__ emb, f16* __restrict__ A2) {
    int n = blockIdx.x;
    int tid = threadIdx.x;
    if (n >= NN) {
        for (int m = tid; m < NP; m += 256) A2[(size_t)n * NP + m] = (f16)0.f;
        return;
    }
    __shared__ float red[4];
    float en[EE];
#pragma unroll
    for (int e = 0; e < EE; e++) en[e] = emb[n * EE + e];
    float g[8];
    float mx = 0.f;
#pragma unroll
    for (int i = 0; i < 8; i++) {
        int m = tid + 256 * i;
        float v = 0.f;
        if (m < NN) {
            float a = 0.f;
#pragma unroll
            for (int e = 0; e < EE; e++) a += en[e] * emb[m * EE + e];
            v = fmaxf(a, 0.f);
            mx = fmaxf(mx, v);
        }
        g[i] = v;
    }
#pragma unroll
    for (int d = 32; d; d >>= 1) mx = fmaxf(mx, __shfl_xor(mx, d));
    if ((tid & 63) == 0) red[tid >> 6] = mx;
    __syncthreads();
    mx = fmaxf(fmaxf(red[0], red[1]), fmaxf(red[2], red[3]));
    float s = 0.f;
#pragma unroll
    for (int i = 0; i < 8; i++) {
        int m = tid + 256 * i;
        if (m < NN) { g[i] = __expf(g[i] - mx); s += g[i]; }
    }
#pragma unroll
    for (int d = 32; d; d >>= 1) s += __shfl_xor(s, d);
    __syncthreads();
    if ((tid & 63) == 0) red[tid >> 6] = s;
    __syncthreads();
    s = red[0] + red[1] + red[2] + red[3];
    float inv = 1.f / s;
#pragma unroll
    for (int i = 0; i < 8; i++) {
        int m = tid + 256 * i;
        A2[(size_t)n * NP + m] = (m < NN) ? (f16)(g[i] * inv) : (f16)0.f;
    }
}

// ---------------- wgen: W^T[n][o][r] = sum_e emb[n,e] * wpool[e,k(r),c(r),o]  (fp16) ----------------
template <int DIN, int O>
__global__ __launch_bounds__(256) void k_wgen(const float* __restrict__ emb,
                                              const float* __restrict__ wpool,
                                              f16* __restrict__ WT) {
    constexpr int DPAD = (DIN == 66) ? 80 : 128;
    constexpr int R = 2 * DPAD;
    int n0 = blockIdx.x * 4;
    int r = threadIdx.x;
    if (r >= R) return;
    int k = (r >= DPAD) ? 1 : 0;
    int c = r - k * DPAD;
    bool valid = (c < DIN);
    float en[4][EE];
#pragma unroll
    for (int j = 0; j < 4; j++)
#pragma unroll
        for (int e = 0; e < EE; e++) en[j][e] = emb[(n0 + j) * EE + e];
    const float* wp = wpool + ((size_t)(k * DIN + (valid ? c : 0))) * O;
    for (int o = 0; o < O; o += 4) {
        float4 a[4] = {};
        if (valid) {
#pragma unroll
            for (int e = 0; e < EE; e++) {
                float4 w4 = *(const float4*)(wp + (size_t)e * 2 * DIN * O + o);
#pragma unroll
                for (int j = 0; j < 4; j++) {
                    a[j].x += en[j][e] * w4.x; a[j].y += en[j][e] * w4.y;
                    a[j].z += en[j][e] * w4.z; a[j].w += en[j][e] * w4.w;
                }
            }
        }
#pragma unroll
        for (int j = 0; j < 4; j++) {
            f16* outp = WT + ((size_t)(n0 + j) * O + o) * R + r;
            outp[0] = (f16)a[j].x; outp[(size_t)R] = (f16)a[j].y;
            outp[(size_t)2 * R] = (f16)a[j].z; outp[(size_t)3 * R] = (f16)a[j].w;
        }
    }
}

// ---------------- pack layer0 x_t into xs0/us0 x-part (row-major only) ----------------
__global__ __launch_bounds__(256) void k_pack(const float* __restrict__ x, int t,
                                              f16* __restrict__ xs, f16* __restrict__ us) {
    int idx = blockIdx.x * 256 + threadIdx.x;  // over b*2*NN, n fastest
    if (idx >= BBATCH * 2 * NN) return;
    int n = idx % NN;
    int bd = idx / NN;
    int d = bd & 1, b = bd >> 1;
    float v = x[(((size_t)b * TT + t) * NN + n) * 2 + d];
    f16 h = (f16)v;
    xs[(size_t)n * (BBATCH * 66) + b * 66 + d] = h;
    us[(size_t)n * (BBATCH * 66) + b * 66 + d] = h;
}

// ---------------- tiled transpose: out[j][m] = in[m][j], in [NP-ish rows][W], clamp m>=NN to 0 ----
template <int W>
__global__ __launch_bounds__(256) void k_tr(const f16* __restrict__ in, f16* __restrict__ out) {
    __shared__ f16 t[64][72];
    int bx = blockIdx.x, by = blockIdx.y;
    int tid = threadIdx.x;
    int ml = tid >> 2, q = tid & 3;
    int m = by * 64 + ml;
    f16x8 a, b2;
#pragma unroll
    for (int i = 0; i < 8; i++) { a[i] = (f16)0.f; b2[i] = (f16)0.f; }
    if (m < NN) {
        const f16* src = in + (size_t)m * W + bx * 64 + q * 16;
        a = *(const f16x8*)src;
        b2 = *(const f16x8*)(src + 8);
    }
    *(f16x8*)&t[ml][q * 16] = a;
    *(f16x8*)&t[ml][q * 16 + 8] = b2;
    __syncthreads();
    int jl = tid >> 2;
    f16x8 r0, r1;
#pragma unroll
    for (int i = 0; i < 8; i++) r0[i] = t[q * 16 + i][jl];
#pragma unroll
    for (int i = 0; i < 8; i++) r1[i] = t[q * 16 + 8 + i][jl];
    f16* dst = out + (size_t)(bx * 64 + jl) * NP + by * 64 + q * 16;
    *(f16x8*)dst = r0;
    *(f16x8*)(dst + 8) = r1;
}

// ---------------- aggregation GEMM: C[2048][J] = A2[2048][2048] @ XT'[...][2048]^T --------------
// row map: global j-col of C -> XT row j' = (j/64)*ST + OFF + j%64  (identity when ST=64, OFF=0)
template <int ST, int OFF>
__global__ __launch_bounds__(256) void k_gemm(const f16* __restrict__ A2, const f16* __restrict__ XT,
                                              f16* __restrict__ C, int J) {
    __shared__ __align__(16) f16 at[128 * 64];
    __shared__ __align__(16) f16 xt[64 * 64];
    int tj = blockIdx.x * 64;
    int tm = blockIdx.y * 128;
    int rowbase = (tj >> 6) * ST + OFF;
    int tid = threadIdx.x;
    int w = tid >> 6, l = tid & 63;
    int lr = l & 15, lg = l >> 4;
    f32x4 acc[2][4];
#pragma unroll
    for (int mt = 0; mt < 2; mt++)
#pragma unroll
        for (int nt = 0; nt < 4; nt++) acc[mt][nt] = (f32x4){0.f, 0.f, 0.f, 0.f};

    for (int k0 = 0; k0 < 2048; k0 += 64) {
        // stage A tile: 16KB
#pragma unroll
        for (int i = 0; i < 4; i++) {
            int e = w * 2048 + i * 512 + l * 8;
            int row = e >> 6, s = (e >> 3) & 7;
            const f16* src = A2 + (size_t)(tm + row) * 2048 + k0 + ((s ^ (row & 7)) << 3);
            gld_lds16(src, &at[w * 2048 + i * 512]);
        }
        // stage X tile: 8KB
#pragma unroll
        for (int i = 0; i < 2; i++) {
            int e = w * 1024 + i * 512 + l * 8;
            int row = e >> 6, s = (e >> 3) & 7;
            const f16* src = XT + (size_t)(rowbase + row) * 2048 + k0 + ((s ^ (row & 7)) << 3);
            gld_lds16(src, &xt[w * 1024 + i * 512]);
        }
        __syncthreads();
#pragma unroll
        for (int kk = 0; kk < 2; kk++) {
            int s = kk * 4 + lg;
            f16x8 av[2], bv[4];
#pragma unroll
            for (int mt = 0; mt < 2; mt++) {
                int row = w * 32 + mt * 16 + lr;
                av[mt] = *(const f16x8*)&at[row * 64 + ((s ^ (row & 7)) << 3)];
            }
#pragma unroll
            for (int nt = 0; nt < 4; nt++) {
                int row = nt * 16 + lr;
                bv[nt] = *(const f16x8*)&xt[row * 64 + ((s ^ (row & 7)) << 3)];
            }
#pragma unroll
            for (int mt = 0; mt < 2; mt++)
#pragma unroll
                for (int nt = 0; nt < 4; nt++)
                    acc[mt][nt] = __builtin_amdgcn_mfma_f32_16x16x32_f16(av[mt], bv[nt], acc[mt][nt], 0, 0, 0);
        }
        __syncthreads();
    }
#pragma unroll
    for (int mt = 0; mt < 2; mt++)
#pragma unroll
        for (int nt = 0; nt < 4; nt++)
#pragma unroll
            for (int q = 0; q < 4; q++) {
                int row = tm + w * 32 + mt * 16 + lg * 4 + q;
                int col = tj + nt * 16 + lr;
                C[(size_t)row * J + col] = (f16)acc[mt][nt][q];
            }
}

// ---------------- fused per-node gate: zr = sigmoid(xg @ W + b); u = z*h; store u (row-major), r --
template <int L>
__global__ __launch_bounds__(256) void k_gate(const f16* __restrict__ xs_rm, const f16* __restrict__ agg,
                                              const f16* __restrict__ WT, const float* __restrict__ bpool,
                                              const float* __restrict__ emb, const float* __restrict__ hbuf,
                                              f16* __restrict__ us_rm, float* __restrict__ rbuf) {
    constexpr int DIN = L ? 128 : 66, CIN = L ? 64 : 2, DPAD = L ? 128 : 80;
    constexpr int R = 2 * DPAD, RPAD = R + 8, KCH = R / 32;
    constexpr int O = 128;
    int n = blockIdx.x;
    int tid = threadIdx.x, w = tid >> 6, l = tid & 63;
    int lr = l & 15, lg = l >> 4;
    __shared__ __align__(16) f16 xg[32 * RPAD];

    f16x8 wf[KCH][2];
    const f16* wbase = WT + (size_t)n * O * R;
#pragma unroll
    for (int kk = 0; kk < KCH; kk++)
#pragma unroll
        for (int nt = 0; nt < 2; nt++) {
            int o = w * 32 + nt * 16 + lr;
            wf[kk][nt] = *(const f16x8*)(wbase + (size_t)o * R + kk * 32 + lg * 8);
        }
    for (int i = tid; i < 32 * RPAD / 8; i += 256) *(float4*)&xg[i * 8] = (float4){0.f, 0.f, 0.f, 0.f};
    __syncthreads();
    if (L == 0) {
        for (int e = tid; e < 32 * DIN; e += 256) {
            int b = e / DIN, c = e % DIN;
            xg[b * RPAD + c] = xs_rm[(size_t)n * 32 * DIN + e];
            xg[b * RPAD + DPAD + c] = agg[(size_t)n * 32 * DIN + e];
        }
    } else {
        for (int e8 = tid; e8 < 32 * DIN / 8; e8 += 256) {
            int b = e8 >> 4, c8 = e8 & 15;
            *(f16x8*)&xg[b * RPAD + c8 * 8] = *(const f16x8*)&xs_rm[(size_t)n * 32 * DIN + e8 * 8];
            *(f16x8*)&xg[b * RPAD + DPAD + c8 * 8] = *(const f16x8*)&agg[(size_t)n * 32 * DIN + e8 * 8];
        }
    }
    __syncthreads();

    f32x4 acc[2][2];
#pragma unroll
    for (int mt = 0; mt < 2; mt++)
#pragma unroll
        for (int nt = 0; nt < 2; nt++) acc[mt][nt] = (f32x4){0.f, 0.f, 0.f, 0.f};
#pragma unroll
    for (int kk = 0; kk < KCH; kk++) {
        f16x8 av[2];
#pragma unroll
        for (int mt = 0; mt < 2; mt++)
            av[mt] = *(const f16x8*)&xg[(mt * 16 + lr) * RPAD + kk * 32 + lg * 8];
#pragma unroll
        for (int mt = 0; mt < 2; mt++)
#pragma unroll
            for (int nt = 0; nt < 2; nt++)
                acc[mt][nt] = __builtin_amdgcn_mfma_f32_16x16x32_f16(av[mt], wf[kk][nt], acc[mt][nt], 0, 0, 0);
    }
    float bias[2];
#pragma unroll
    for (int nt = 0; nt < 2; nt++) {
        int o = w * 32 + nt * 16 + lr;
        float bs = 0.f;
#pragma unroll
        for (int e = 0; e < EE; e++) bs += emb[n * EE + e] * bpool[e * 2 * HH + o];
        bias[nt] = bs;
    }
#pragma unroll
    for (int mt = 0; mt < 2; mt++)
#pragma unroll
        for (int nt = 0; nt < 2; nt++)
#pragma unroll
            for (int q = 0; q < 4; q++) {
                int o = w * 32 + nt * 16 + lr;
                int b = mt * 16 + lg * 4 + q;
                float v = acc[mt][nt][q] + bias[nt];
                float sg = 1.f / (1.f + __expf(-v));
                if (o < HH) {  // z half
                    float u = sg * hbuf[((size_t)n * 32 + b) * HH + o];
                    us_rm[(size_t)n * 32 * DIN + b * DIN + CIN + o] = (f16)u;
                } else {       // r half
                    rbuf[((size_t)n * 32 + b) * HH + (o - HH)] = sg;
                }
            }
}

// ---------------- fused per-node update: hc = tanh(xg @ W + b); h' = r*h + (1-r)*hc ---------------
template <int L>
__global__ __launch_bounds__(256) void k_upd(const f16* __restrict__ us_rm, const f16* __restrict__ agg,
                                             const f16* __restrict__ uagg, const f16* __restrict__ WT,
                                             const float* __restrict__ bpool, const float* __restrict__ emb,
                                             float* hbuf, const float* __restrict__ rbuf,
                                             f16* xs_self, f16* xsn, f16* usn,
                                             float* dout, int t) {
    constexpr int DIN = L ? 128 : 66, CIN = L ? 64 : 2, DPAD = L ? 128 : 80;
    constexpr int R = 2 * DPAD, RPAD = R + 8, KCH = R / 32;
    constexpr int O = 64;
    int n = blockIdx.x;
    int tid = threadIdx.x, w = tid >> 6, l = tid & 63;
    int lr = l & 15, lg = l >> 4;
    __shared__ __align__(16) f16 xg[32 * RPAD];

    f16x8 wf[KCH];
    const f16* wbase = WT + (size_t)n * O * R;
    int o = w * 16 + lr;
#pragma unroll
    for (int kk = 0; kk < KCH; kk++)
        wf[kk] = *(const f16x8*)(wbase + (size_t)o * R + kk * 32 + lg * 8);

    for (int i = tid; i < 32 * RPAD / 8; i += 256) *(float4*)&xg[i * 8] = (float4){0.f, 0.f, 0.f, 0.f};
    __syncthreads();
    if (L == 0) {
        for (int e = tid; e < 32 * DIN; e += 256) {
            int b = e / DIN, c = e % DIN;
            xg[b * RPAD + c] = us_rm[(size_t)n * 32 * DIN + e];
            f16 v = (c < CIN) ? agg[(size_t)n * 32 * DIN + b * DIN + c]
                              : uagg[(size_t)n * 32 * HH + b * HH + (c - CIN)];
            xg[b * RPAD + DPAD + c] = v;
        }
    } else {
        for (int e8 = tid; e8 < 32 * DIN / 8; e8 += 256) {
            int b = e8 >> 4, c8 = e8 & 15;
            *(f16x8*)&xg[b * RPAD + c8 * 8] = *(const f16x8*)&us_rm[(size_t)n * 32 * DIN + e8 * 8];
            f16x8 v = (c8 < 8) ? *(const f16x8*)&agg[(size_t)n * 32 * DIN + b * DIN + c8 * 8]
                               : *(const f16x8*)&uagg[(size_t)n * 32 * HH + b * HH + (c8 - 8) * 8];
            *(f16x8*)&xg[b * RPAD + DPAD + c8 * 8] = v;
        }
    }
    __syncthreads();

    f32x4 acc[2];
#pragma unroll
    for (int mt = 0; mt < 2; mt++) acc[mt] = (f32x4){0.f, 0.f, 0.f, 0.f};
#pragma unroll
    for (int kk = 0; kk < KCH; kk++) {
        f16x8 av[2];
#pragma unroll
        for (int mt = 0; mt < 2; mt++)
            av[mt] = *(const f16x8*)&xg[(mt * 16 + lr) * RPAD + kk * 32 + lg * 8];
#pragma unroll
        for (int mt = 0; mt < 2; mt++)
            acc[mt] = __builtin_amdgcn_mfma_f32_16x16x32_f16(av[mt], wf[kk], acc[mt], 0, 0, 0);
    }
    float bias = 0.f;
#pragma unroll
    for (int e = 0; e < EE; e++) bias += emb[n * EE + e] * bpool[e * HH + o];
#pragma unroll
    for (int mt = 0; mt < 2; mt++)
#pragma unroll
        for (int q = 0; q < 4; q++) {
            int b = mt * 16 + lg * 4 + q;
            float v = acc[mt][q] + bias;
            float ex = __expf(2.f * v);
            float hc = 1.f - 2.f / (ex + 1.f);  // tanh
            size_t hidx = ((size_t)n * 32 + b) * HH + o;
            float r = rbuf[hidx], h = hbuf[hidx];
            float hn = r * h + (1.f - r) * hc;
            hbuf[hidx] = hn;
            f16 hh = (f16)hn;
            xs_self[(size_t)n * 32 * DIN + b * DIN + CIN + o] = hh;
            if (L == 0) {
                xsn[(size_t)n * 32 * 128 + b * 128 + o] = hh;
                usn[(size_t)n * 32 * 128 + b * 128 + o] = hh;
            } else {
                dout[(((size_t)b * TT + t) * NN + n) * HH + o] = hn;
                if (t == TT - 1)
                    dout[(size_t)BBATCH * TT * NN * HH + ((size_t)b * NN + n) * HH + o] = hn;
            }
        }
}

extern "C" void kernel_launch(void* const* d_in, const int* in_sizes, int n_in,
                              void* d_out, int out_size, void* d_ws, size_t ws_size,
                              hipStream_t stream) {
    (void)in_sizes; (void)n_in; (void)out_size; (void)ws_size;
    const float* x   = (const float*)d_in[0];
    const float* emb = (const float*)d_in[1];
    const float* gw0 = (const float*)d_in[2];
    const float* gb0 = (const float*)d_in[3];
    const float* uw0 = (const float*)d_in[4];
    const float* ub0 = (const float*)d_in[5];
    const float* gw1 = (const float*)d_in[6];
    const float* gb1 = (const float*)d_in[7];
    const float* uw1 = (const float*)d_in[8];
    const float* ub1 = (const float*)d_in[9];
    float* out = (float*)d_out;

    char* p = (char*)d_ws;
    auto alloc = [&](size_t bytes) { char* r = p; p += (bytes + 255) & ~(size_t)255; return r; };
    f16* A2    = (f16*)alloc((size_t)NP * NP * 2);
    f16* Wg0   = (f16*)alloc((size_t)NN * 128 * 160 * 2);
    f16* Wu0   = (f16*)alloc((size_t)NN * 64 * 160 * 2);
    f16* Wg1   = (f16*)alloc((size_t)NN * 128 * 256 * 2);
    f16* Wu1   = (f16*)alloc((size_t)NN * 64 * 256 * 2);
    f16* xs0   = (f16*)alloc((size_t)NN * 32 * 66 * 2);
    f16* xsT0  = (f16*)alloc((size_t)2112 * NP * 2);
    f16* agg0  = (f16*)alloc((size_t)NP * 2112 * 2);
    f16* us0   = (f16*)alloc((size_t)NN * 32 * 66 * 2);
    f16* usT0  = (f16*)alloc((size_t)2112 * NP * 2);
    f16* uagg0 = (f16*)alloc((size_t)NP * 2048 * 2);
    f16* xs1   = (f16*)alloc((size_t)NN * 32 * 128 * 2);
    f16* xsT1  = (f16*)alloc((size_t)4096 * NP * 2);
    f16* agg1  = (f16*)alloc((size_t)NP * 4096 * 2);
    f16* us1   = (f16*)alloc((size_t)NN * 32 * 128 * 2);
    f16* usT1  = (f16*)alloc((size_t)4096 * NP * 2);
    f16* uagg1 = (f16*)alloc((size_t)NP * 2048 * 2);
    float* h0  = (float*)alloc((size_t)NN * 32 * 64 * 4);
    float* r0  = (float*)alloc((size_t)NN * 32 * 64 * 4);
    float* h1  = (float*)alloc((size_t)NN * 32 * 64 * 4);
    float* r1  = (float*)alloc((size_t)NN * 32 * 64 * 4);

    // zero recurrent-state-bearing row-major buffers (h-parts must be 0 at t=0)
    hipMemsetAsync(xs0, 0, (size_t)NN * 32 * 66 * 2, stream);
    hipMemsetAsync(xs1, 0, (size_t)NN * 32 * 128 * 2, stream);
    hipMemsetAsync(h0, 0, (size_t)NN * 32 * 64 * 4, stream);
    hipMemsetAsync(h1, 0, (size_t)NN * 32 * 64 * 4, stream);

    k_supports<<<NP, 256, 0, stream>>>(emb, A2);
    k_wgen<66, 128><<<NN / 4, 256, 0, stream>>>(emb, gw0, Wg0);
    k_wgen<66, 64><<<NN / 4, 256, 0, stream>>>(emb, uw0, Wu0);
    k_wgen<128, 128><<<NN / 4, 256, 0, stream>>>(emb, gw1, Wg1);
    k_wgen<128, 64><<<NN / 4, 256, 0, stream>>>(emb, uw1, Wu1);

    for (int t = 0; t < TT; t++) {
        // ---- layer 0 ----
        k_pack<<<500, 256, 0, stream>>>(x, t, xs0, us0);
        k_tr<2112><<<dim3(33, 32), 256, 0, stream>>>(xs0, xsT0);
        k_gemm<64, 0><<<dim3(2112 / 64, 16), 256, 0, stream>>>(A2, xsT0, agg0, 2112);
        k_gate<0><<<NN, 256, 0, stream>>>(xs0, agg0, Wg0, gb0, emb, h0, us0, r0);
        k_tr<2112><<<dim3(33, 32), 256, 0, stream>>>(us0, usT0);
        k_gemm<66, 2><<<dim3(2048 / 64, 16), 256, 0, stream>>>(A2, usT0, uagg0, 2048);
        k_upd<0><<<NN, 256, 0, stream>>>(us0, agg0, uagg0, Wu0, ub0, emb, h0, r0,
                                         xs0, xs1, us1, nullptr, t);
        // ---- layer 1 ----
        k_tr<4096><<<dim3(64, 32), 256, 0, stream>>>(xs1, xsT1);
        k_gemm<64, 0><<<dim3(4096 / 64, 16), 256, 0, stream>>>(A2, xsT1, agg1, 4096);
        k_gate<1><<<NN, 256, 0, stream>>>(xs1, agg1, Wg1, gb1, emb, h1, us1, r1);
        k_tr<4096><<<dim3(64, 32), 256, 0, stream>>>(us1, usT1);
        k_gemm<128, 64><<<dim3(2048 / 64, 16), 256, 0, stream>>>(A2, usT1, uagg1, 2048);
        k_upd<1><<<NN, 256, 0, stream>>>(us1, agg1, uagg1, Wu1, ub1, emb, h1, r1,
                                         xs1, nullptr, nullptr, out, t);
    }
}